// Round 17
// baseline (241.036 us; speedup 1.0000x reference)
//
#include <hip/hip_runtime.h>
#include <math.h>

#define NUM_AGENTS   128
#define NUM_HIVES    64
#define NUM_ENTITIES 192
#define G 4   // batches per block (grid = B/G); LDS buffers are [G][...]

// One block handles G=4 consecutive batches with r14's per-batch access
// pattern (2 lanes per agent, serial in-register argmax, 1 shfl merge).
// Per-batch LDS buffers -> only TWO barriers per block for all 4 batches.
__global__ __launch_bounds__(256) void bee_kernel(
    const float* __restrict__ movements,    // (B, 192, 2)
    const float* __restrict__ votes,        // (B, 128, 64)
    const float* __restrict__ hive_values,  // (B, 64, 1)
    float* __restrict__ ws_partial,         // (B,)
    float* __restrict__ out)                // [0]=scalar, [1..B]=max_freq
{
    const int tid  = threadIdx.x;
    const int lane = tid & 63;
    const int wave = tid >> 6;
    const int b0   = blockIdx.x * G;

    __shared__ float hv[G][NUM_HIVES];
    __shared__ int   counts[G][NUM_HIVES];
    __shared__ float mc_s[G][4];
    __shared__ float vs_s[G][4];

    // prologue: 256 threads zero G*64 counters and stage G*64 hive values
    counts[tid >> 6][tid & 63] = 0;
    hv[tid >> 6][tid & 63] =
        hive_values[(size_t)(b0 + (tid >> 6)) * NUM_HIVES + (tid & 63)];
    __syncthreads();   // barrier #1

    const int agent = tid >> 1;     // 0..127
    const int half  = tid & 1;      // 0: hives 0..31, 1: hives 32..63

    #pragma unroll
    for (int t = 0; t < G; ++t) {
        const size_t b = b0 + t;

        // movement cost partial: 192 entities, float2 coalesced
        float mc = 0.0f;
        if (tid < NUM_ENTITIES) {
            float2 m = ((const float2*)movements)[b * NUM_ENTITIES + tid];
            mc = sqrtf(m.x * m.x + m.y * m.y);
        }

        // per-agent argmax: 32 contiguous floats per lane, strict > (first-index ties)
        const float4* row = (const float4*)(votes + b * NUM_AGENTS * NUM_HIVES)
                            + agent * 16 + half * 8;
        float bv = -INFINITY;
        int   bi = 0;
        #pragma unroll
        for (int k = 0; k < 8; ++k) {
            float4 v = row[k];
            int base = half * 32 + k * 4;
            if (v.x > bv) { bv = v.x; bi = base + 0; }
            if (v.y > bv) { bv = v.y; bi = base + 1; }
            if (v.z > bv) { bv = v.z; bi = base + 2; }
            if (v.w > bv) { bv = v.w; bi = base + 3; }
        }
        // merge with partner lane; lower index wins ties (half 0 holds lower indices)
        {
            float ov = __shfl_xor(bv, 1, 64);
            int   oi = __shfl_xor(bi, 1, 64);
            if (ov > bv || (ov == bv && oi < bi)) { bv = ov; bi = oi; }
        }

        float vsum = 0.0f;
        if (half == 0) {
            atomicAdd(&counts[t][bi], 1);
            vsum = hv[t][bi];
        }

        // wave reduction of mc and vsum; per-batch LDS slots (no extra barrier)
        #pragma unroll
        for (int off = 32; off > 0; off >>= 1) {
            mc   += __shfl_down(mc,   off, 64);
            vsum += __shfl_down(vsum, off, 64);
        }
        if (lane == 0) { mc_s[t][wave] = mc; vs_s[t][wave] = vsum; }
    }

    __syncthreads();   // barrier #2: all counts/mc_s/vs_s visible

    if (wave == 0) {
        #pragma unroll
        for (int t = 0; t < G; ++t) {
            int c = counts[t][lane];
            #pragma unroll
            for (int off = 32; off > 0; off >>= 1) {
                int oc = __shfl_down(c, off, 64);
                c = c > oc ? c : oc;
            }
            if (lane == 0) {
                float mc_t = mc_s[t][0] + mc_s[t][1] + mc_s[t][2] + mc_s[t][3];
                float vs_t = vs_s[t][0] + vs_s[t][1] + vs_s[t][2] + vs_s[t][3];
                float mf = (float)c / (float)NUM_AGENTS;
                out[1 + b0 + t] = mf;
                // discount = 100 / (1 + exp(30*(mf - 0.7)))
                float discount = 100.0f / (1.0f + expf(30.0f * (mf - 0.7f)));
                ws_partial[b0 + t] = mc_t - vs_t / discount;
            }
        }
    }
}

// Single block reduces B partials -> out[0]. Deterministic, no atomics.
__global__ __launch_bounds__(256) void reduce_kernel(
    const float* __restrict__ ws_partial, float* __restrict__ out, int B)
{
    const int tid  = threadIdx.x;
    const int lane = tid & 63;
    const int wave = tid >> 6;
    __shared__ float p_s[4];

    float s = 0.0f;
    const float4* w4 = (const float4*)ws_partial;
    for (int i = tid; i < B / 4; i += 256) {
        float4 v = w4[i];
        s += (v.x + v.y) + (v.z + v.w);
    }
    #pragma unroll
    for (int off = 32; off > 0; off >>= 1) s += __shfl_down(s, off, 64);
    if (lane == 0) p_s[wave] = s;
    __syncthreads();
    if (tid == 0) out[0] = p_s[0] + p_s[1] + p_s[2] + p_s[3];
}

extern "C" void kernel_launch(void* const* d_in, const int* in_sizes, int n_in,
                              void* d_out, int out_size, void* d_ws, size_t ws_size,
                              hipStream_t stream) {
    const float* movements   = (const float*)d_in[0];
    // d_in[1] = utterances (unused by reference)
    const float* votes       = (const float*)d_in[2];
    const float* hive_values = (const float*)d_in[3];
    // d_in[4] = locations (unused by reference)
    float* out = (float*)d_out;
    float* ws_partial = (float*)d_ws;   // B floats of scratch

    const int B = in_sizes[3] / NUM_HIVES;   // 4096

    bee_kernel<<<B / G, 256, 0, stream>>>(movements, votes, hive_values, ws_partial, out);
    reduce_kernel<<<1, 256, 0, stream>>>(ws_partial, out, B);
}

// Round 18
// 232.546 us; speedup vs baseline: 1.0365x; 1.0365x over previous
//
#include <hip/hip_runtime.h>
#include <math.h>

#define NUM_AGENTS   128
#define NUM_HIVES    64
#define NUM_ENTITIES 192

// One block per batch element. 256 threads = 4 waves.
// 2 lanes per agent: each lane serially argmaxes 32 contiguous floats in
// registers (zero cross-lane ops), then ONE shfl_xor merge per agent.
// Best measured variant (r16: 232.1 us headline).
__global__ __launch_bounds__(256) void bee_kernel(
    const float* __restrict__ movements,    // (B, 192, 2)
    const float* __restrict__ votes,        // (B, 128, 64)
    const float* __restrict__ hive_values,  // (B, 64, 1)
    float* __restrict__ ws_partial,         // (B,)
    float* __restrict__ out)                // [0]=scalar, [1..B]=max_freq
{
    const int b    = blockIdx.x;
    const int tid  = threadIdx.x;
    const int lane = tid & 63;
    const int wave = tid >> 6;

    __shared__ float hv[NUM_HIVES];
    __shared__ int   counts[NUM_HIVES];
    __shared__ float mc_s[4];
    __shared__ float vs_s[4];

    if (tid < NUM_HIVES) {
        hv[tid]     = hive_values[(size_t)b * NUM_HIVES + tid];
        counts[tid] = 0;
    }
    __syncthreads();

    // ---- movement cost partial: 192 entities, float2 coalesced ----
    float mc = 0.0f;
    if (tid < NUM_ENTITIES) {
        float2 m = ((const float2*)movements)[(size_t)b * NUM_ENTITIES + tid];
        mc = sqrtf(m.x * m.x + m.y * m.y);
    }

    // ---- per-agent argmax: agent = tid>>1, half row (32 floats) per lane ----
    const int agent = tid >> 1;     // 0..127, one pass covers all agents
    const int half  = tid & 1;      // 0: hives 0..31, 1: hives 32..63
    const float4* row = (const float4*)(votes + (size_t)b * NUM_AGENTS * NUM_HIVES)
                        + agent * 16 + half * 8;

    // serial in-register argmax over 32 floats (strict > = first-index ties)
    float bv = -INFINITY;
    int   bi = 0;
    #pragma unroll
    for (int k = 0; k < 8; ++k) {
        float4 v = row[k];
        int base = half * 32 + k * 4;
        if (v.x > bv) { bv = v.x; bi = base + 0; }
        if (v.y > bv) { bv = v.y; bi = base + 1; }
        if (v.z > bv) { bv = v.z; bi = base + 2; }
        if (v.w > bv) { bv = v.w; bi = base + 3; }
    }

    // single merge step with the partner lane (xor 1); lower index wins ties
    {
        float ov = __shfl_xor(bv, 1, 64);
        int   oi = __shfl_xor(bi, 1, 64);
        if (ov > bv || (ov == bv && oi < bi)) { bv = ov; bi = oi; }
    }

    float vsum = 0.0f;
    if (half == 0) {
        atomicAdd(&counts[bi], 1);
        vsum = hv[bi];
    }

    // ---- block reduction of mc and vsum ----
    #pragma unroll
    for (int off = 32; off > 0; off >>= 1) {
        mc   += __shfl_down(mc,   off, 64);
        vsum += __shfl_down(vsum, off, 64);
    }
    if (lane == 0) { mc_s[wave] = mc; vs_s[wave] = vsum; }
    __syncthreads();   // also makes counts[] atomics visible

    if (wave == 0) {
        int c = counts[lane];
        #pragma unroll
        for (int off = 32; off > 0; off >>= 1) {
            int oc = __shfl_down(c, off, 64);
            c = c > oc ? c : oc;
        }
        if (lane == 0) {
            float mc_t = mc_s[0] + mc_s[1] + mc_s[2] + mc_s[3];
            float vs_t = vs_s[0] + vs_s[1] + vs_s[2] + vs_s[3];
            float mf = (float)c / (float)NUM_AGENTS;
            out[1 + b] = mf;
            // discount = 100*(1 - sigmoid(30*(mf-0.7))) = 100 / (1 + exp(30*(mf-0.7)))
            float discount = 100.0f / (1.0f + expf(30.0f * (mf - 0.7f)));
            ws_partial[b] = mc_t - vs_t / discount;
        }
    }
}

// Single block reduces B partials -> out[0]. Deterministic, no atomics.
__global__ __launch_bounds__(256) void reduce_kernel(
    const float* __restrict__ ws_partial, float* __restrict__ out, int B)
{
    const int tid  = threadIdx.x;
    const int lane = tid & 63;
    const int wave = tid >> 6;
    __shared__ float p_s[4];

    float s = 0.0f;
    const float4* w4 = (const float4*)ws_partial;
    for (int i = tid; i < B / 4; i += 256) {
        float4 v = w4[i];
        s += (v.x + v.y) + (v.z + v.w);
    }
    #pragma unroll
    for (int off = 32; off > 0; off >>= 1) s += __shfl_down(s, off, 64);
    if (lane == 0) p_s[wave] = s;
    __syncthreads();
    if (tid == 0) out[0] = p_s[0] + p_s[1] + p_s[2] + p_s[3];
}

extern "C" void kernel_launch(void* const* d_in, const int* in_sizes, int n_in,
                              void* d_out, int out_size, void* d_ws, size_t ws_size,
                              hipStream_t stream) {
    const float* movements   = (const float*)d_in[0];
    // d_in[1] = utterances (unused by reference)
    const float* votes       = (const float*)d_in[2];
    const float* hive_values = (const float*)d_in[3];
    // d_in[4] = locations (unused by reference)
    float* out = (float*)d_out;
    float* ws_partial = (float*)d_ws;   // B floats of scratch

    const int B = in_sizes[3] / NUM_HIVES;   // 4096

    bee_kernel<<<B, 256, 0, stream>>>(movements, votes, hive_values, ws_partial, out);
    reduce_kernel<<<1, 256, 0, stream>>>(ws_partial, out, B);
}